// Round 1
// baseline (266.794 us; speedup 1.0000x reference)
//
#include <hip/hip_runtime.h>

#define N_NODES 50000
#define N_EDGES 800000
#define D 64

// ---- Kernel 1: count in-degree over edge targets --------------------------
__global__ void deg_count_kernel(const int* __restrict__ col, float* __restrict__ deg, int E) {
    int e = blockIdx.x * blockDim.x + threadIdx.x;
    if (e < E) {
        atomicAdd(&deg[col[e]], 1.0f);
    }
}

// ---- Kernel 2: dinv = rsqrt(deg + 1)  (self-loop folded in) ---------------
__global__ void dinv_kernel(const float* __restrict__ deg, float* __restrict__ dinv, int n) {
    int i = blockIdx.x * blockDim.x + threadIdx.x;
    if (i < n) {
        dinv[i] = rsqrtf(deg[i] + 1.0f);
    }
}

// ---- Kernel 3: h = x @ W^T; out = h*dinv^2 + b (self-loop contribution) ---
// Block = 256 threads = 4 nodes x 64 output channels. W staged in LDS padded.
__global__ void __launch_bounds__(256) gemm_selfloop_kernel(
    const float* __restrict__ x, const float* __restrict__ W,
    const float* __restrict__ b, const float* __restrict__ dinv,
    float* __restrict__ h, float* __restrict__ out, int n)
{
    __shared__ float Ws[D * 65];   // padded stride 65 -> conflict-free
    __shared__ float xs[4][D];

    int tid = threadIdx.x;
    // Cooperative load of W (4096 floats / 256 threads = 16 each)
    #pragma unroll
    for (int k = 0; k < 16; ++k) {
        int idx = tid + k * 256;
        int o = idx >> 6, i = idx & 63;
        Ws[o * 65 + i] = W[idx];
    }

    int ln = tid >> 6;        // local node 0..3 (one wave each)
    int o  = tid & 63;        // output channel
    int node = blockIdx.x * 4 + ln;
    if (node < n) {
        xs[ln][o] = x[node * D + o];
    }
    __syncthreads();

    if (node >= n) return;

    float sum = 0.0f;
    #pragma unroll
    for (int i = 0; i < D; ++i) {
        sum += xs[ln][i] * Ws[o * 65 + i];
    }

    float dv = dinv[node];
    h[node * D + o] = sum;
    out[node * D + o] = sum * dv * dv + b[o];
}

// ---- Kernel 4: edge scatter with atomics ----------------------------------
// One wave per edge, one lane per channel. h reads fully coalesced.
__global__ void scatter_kernel(const int* __restrict__ row, const int* __restrict__ col,
                               const float* __restrict__ dinv, const float* __restrict__ h,
                               float* __restrict__ out, int E)
{
    int gid = blockIdx.x * blockDim.x + threadIdx.x;
    int e = gid >> 6;
    int o = gid & 63;
    if (e < E) {
        int r = row[e], c = col[e];
        float w = dinv[r] * dinv[c];
        atomicAdd(&out[c * D + o], h[r * D + o] * w);
    }
}

// ---- Kernel 5: in-place PReLU ---------------------------------------------
__global__ void prelu_kernel(float* __restrict__ out, const float* __restrict__ a, int total) {
    int i = blockIdx.x * blockDim.x + threadIdx.x;
    if (i < total) {
        float v = out[i];
        float alpha = a[0];
        out[i] = v >= 0.0f ? v : alpha * v;
    }
}

extern "C" void kernel_launch(void* const* d_in, const int* in_sizes, int n_in,
                              void* d_out, int out_size, void* d_ws, size_t ws_size,
                              hipStream_t stream) {
    const float* x        = (const float*)d_in[0];
    const int*   eidx     = (const int*)d_in[1];   // [2, E] flat
    const float* W        = (const float*)d_in[2];
    const float* b        = (const float*)d_in[3];
    const float* prelu_a  = (const float*)d_in[4];

    const int E = in_sizes[1] / 2;
    const int n = N_NODES;
    const int* row = eidx;
    const int* col = eidx + E;

    float* out = (float*)d_out;

    // Workspace layout: deg [N] | dinv [N] | h [N*64]
    float* deg  = (float*)d_ws;
    float* dinv = deg + n;
    float* h    = dinv + n;

    // 1. zero degree + count
    hipMemsetAsync(deg, 0, n * sizeof(float), stream);
    deg_count_kernel<<<(E + 255) / 256, 256, 0, stream>>>(col, deg, E);

    // 2. dinv
    dinv_kernel<<<(n + 255) / 256, 256, 0, stream>>>(deg, dinv, n);

    // 3. GEMM + self-loop init of out (fully overwrites d_out)
    gemm_selfloop_kernel<<<(n + 3) / 4, 256, 0, stream>>>(x, W, b, dinv, h, out, n);

    // 4. edge scatter (E * 64 threads)
    long long total_scatter = (long long)E * D;
    scatter_kernel<<<(int)((total_scatter + 255) / 256), 256, 0, stream>>>(row, col, dinv, h, out, E);

    // 5. PReLU in place
    int total = n * D;
    prelu_kernel<<<(total + 255) / 256, 256, 0, stream>>>(out, prelu_a, total);
}

// Round 2
// 159.123 us; speedup vs baseline: 1.6767x; 1.6767x over previous
//
#include <hip/hip_runtime.h>

#define D 64
#define CAP 64          // bucket capacity per node (avg degree 16, Poisson tail -> overflow ~impossible)

// ---- K1: fill buckets; cnt[] doubles as the degree histogram --------------
__global__ void fill_kernel(const int* __restrict__ row, const int* __restrict__ col,
                            int* __restrict__ cnt, int* __restrict__ srcs,
                            int* __restrict__ ovf_cnt, int2* __restrict__ ovf, int E)
{
    int e = blockIdx.x * blockDim.x + threadIdx.x;
    if (e >= E) return;
    int r = row[e], c = col[e];
    int slot = atomicAdd(&cnt[c], 1);
    if (slot < CAP) {
        srcs[c * CAP + slot] = r;
    } else {
        int oi = atomicAdd(ovf_cnt, 1);   // capacity == E, can never overflow
        ovf[oi] = make_int2(r, c);
    }
}

// ---- K2: dinv = rsqrt(deg + 1) (self-loop folded in) ----------------------
__global__ void dinv_kernel(const int* __restrict__ cnt, float* __restrict__ dinv, int n) {
    int i = blockIdx.x * blockDim.x + threadIdx.x;
    if (i < n) {
        dinv[i] = rsqrtf((float)cnt[i] + 1.0f);
    }
}

// ---- K3: h = x @ W^T ------------------------------------------------------
// Block = 256 threads = 4 nodes x 64 output channels. W staged in LDS padded.
__global__ void __launch_bounds__(256) gemm_kernel(
    const float* __restrict__ x, const float* __restrict__ W,
    float* __restrict__ h, int n)
{
    __shared__ float Ws[D * 65];   // padded stride 65 -> conflict-free
    __shared__ float xs[4][D];

    int tid = threadIdx.x;
    #pragma unroll
    for (int k = 0; k < 16; ++k) {
        int idx = tid + k * 256;
        int o = idx >> 6, i = idx & 63;
        Ws[o * 65 + i] = W[idx];
    }

    int ln = tid >> 6;
    int o  = tid & 63;
    int node = blockIdx.x * 4 + ln;
    if (node < n) {
        xs[ln][o] = x[node * D + o];
    }
    __syncthreads();

    if (node >= n) return;

    float sum = 0.0f;
    #pragma unroll
    for (int i = 0; i < D; ++i) {
        sum += xs[ln][i] * Ws[o * 65 + i];
    }
    h[node * D + o] = sum;
}

// ---- K4: per-target gather-aggregate (no atomics) -------------------------
// One wave per target node; lane = output channel.
__global__ void __launch_bounds__(256) gather_kernel(
    const int* __restrict__ cnt, const int* __restrict__ srcs,
    const float* __restrict__ dinv, const float* __restrict__ h,
    const float* __restrict__ b, float* __restrict__ out, int n)
{
    int wave = (blockIdx.x * blockDim.x + threadIdx.x) >> 6;
    int lane = threadIdx.x & 63;
    if (wave >= n) return;
    int c = wave;

    int deg = cnt[c];
    int m = deg < CAP ? deg : CAP;
    float dc = dinv[c];

    // lane j holds source-index j and its edge weight (one coalesced 256B read)
    int   s  = 0;
    float wl = 0.0f;
    if (lane < m) {
        s  = srcs[c * CAP + lane];
        wl = dinv[s] * dc;
    }

    // self-loop term + bias
    float acc = h[c * D + lane] * dc * dc + b[lane];

    for (int k = 0; k < m; ++k) {
        int   sk = __shfl(s,  k);
        float wk = __shfl(wl, k);
        acc += h[sk * D + lane] * wk;
    }

    out[c * D + lane] = acc;   // pre-activation (PReLU applied later)
}

// ---- K5: overflow fallback (normally zero iterations) ---------------------
__global__ void overflow_kernel(const int* __restrict__ ovf_cnt, const int2* __restrict__ ovf,
                                const float* __restrict__ dinv, const float* __restrict__ h,
                                float* __restrict__ out)
{
    int nov = *ovf_cnt;
    int wave = (blockIdx.x * blockDim.x + threadIdx.x) >> 6;
    int lane = threadIdx.x & 63;
    int nwaves = (gridDim.x * blockDim.x) >> 6;
    for (int i = wave; i < nov; i += nwaves) {
        int r = ovf[i].x, c = ovf[i].y;
        atomicAdd(&out[c * D + lane], h[r * D + lane] * dinv[r] * dinv[c]);
    }
}

// ---- K6: in-place PReLU ---------------------------------------------------
__global__ void prelu_kernel(float* __restrict__ out, const float* __restrict__ a, int total) {
    int i = blockIdx.x * blockDim.x + threadIdx.x;
    if (i < total) {
        float v = out[i];
        float alpha = a[0];
        out[i] = v >= 0.0f ? v : alpha * v;
    }
}

extern "C" void kernel_launch(void* const* d_in, const int* in_sizes, int n_in,
                              void* d_out, int out_size, void* d_ws, size_t ws_size,
                              hipStream_t stream) {
    const float* x       = (const float*)d_in[0];
    const int*   eidx    = (const int*)d_in[1];   // [2, E] flat
    const float* W       = (const float*)d_in[2];
    const float* b       = (const float*)d_in[3];
    const float* prelu_a = (const float*)d_in[4];

    const int E = in_sizes[1] / 2;
    const int n = in_sizes[0] / D;                // 50000
    const int* row = eidx;
    const int* col = eidx + E;

    float* out = (float*)d_out;

    // Workspace layout (all 4-byte elements; int2 needs 8B alignment):
    //   cnt      int[n]
    //   ovf_cnt  int[1]
    //   pad      int[1]            (keeps ovf 8-byte aligned: (n+2)*4 % 8 == 0)
    //   ovf      int2[E]
    //   dinv     float[n]
    //   srcs     int[n*CAP]
    //   h        float[n*D]
    int*   cnt     = (int*)d_ws;
    int*   ovf_cnt = cnt + n;
    int2*  ovf     = (int2*)(cnt + n + 2);
    float* dinv    = (float*)(ovf + E);
    int*   srcs    = (int*)(dinv + n);
    float* h       = (float*)(srcs + (size_t)n * CAP);

    // zero cnt + ovf_cnt in one shot (adjacent)
    hipMemsetAsync(cnt, 0, (size_t)(n + 1) * sizeof(int), stream);

    fill_kernel<<<(E + 255) / 256, 256, 0, stream>>>(row, col, cnt, srcs, ovf_cnt, ovf, E);

    dinv_kernel<<<(n + 255) / 256, 256, 0, stream>>>(cnt, dinv, n);

    gemm_kernel<<<(n + 3) / 4, 256, 0, stream>>>(x, W, h, n);

    gather_kernel<<<(n * 64 + 255) / 256, 256, 0, stream>>>(cnt, srcs, dinv, h, b, out, n);

    overflow_kernel<<<64, 256, 0, stream>>>(ovf_cnt, ovf, dinv, h, out);

    prelu_kernel<<<(n * D + 255) / 256, 256, 0, stream>>>(out, prelu_a, n * D);
}